// Round 8
// baseline (1583.582 us; speedup 1.0000x reference)
//
#include <hip/hip_runtime.h>
#include <math.h>

#define BB 256
#define TT 2048
#define VOCAB 7
#define EMBD 20
#define HID 128
#define OUTD 6
#define CHUNK 64
#define NCHUNK (TT / CHUNK)

typedef _Float16 h2 __attribute__((ext_vector_type(2)));

// Single-instruction fast ops (gfx950, ~1 ULP)
__device__ __forceinline__ float v_exp2(float x) {
    float r; asm("v_exp_f32 %0, %1" : "=v"(r) : "v"(x)); return r;
}
__device__ __forceinline__ float v_rcp(float x) {
    float r; asm("v_rcp_f32 %0, %1" : "=v"(r) : "v"(x)); return r;
}
__device__ __forceinline__ float sigmoid_f(float x) {
    return v_rcp(1.0f + v_exp2(-1.44269504f * x));
}
__device__ __forceinline__ float tanh_f(float x) {
    float ax = fabsf(x);
    float t = v_exp2(-2.88539008f * ax);          // exp(-2|x|)
    float r = (1.0f - t) * v_rcp(1.0f + t);
    return __builtin_copysignf(r, x);
}

// Guaranteed v_dot2_f32_f16 emission (f32 accumulate)
__device__ __forceinline__ float dot2(h2 a, h2 b, float c) {
    float d;
    asm("v_dot2_f32_f16 %0, %1, %2, %3" : "=v"(d) : "v"(a), "v"(b), "v"(c));
    return d;
}

#define KEEP(x) asm volatile("" : "+v"(x))

// One block per batch element (grid == 256 == #CUs), persistent over all T.
// Thread (j,r) = (tid>>2, tid&3): ALL 4 gates of unit j over h-slice [32r,32r+32).
// Weights: 4 gates x 16 h2 pairs = 64 VGPRs.
__global__ __launch_bounds__(512) void lstm_persist(
    const int* __restrict__ inputs, const float* __restrict__ c0,
    const float* __restrict__ W_ih, const float* __restrict__ W_hh,
    const float* __restrict__ b_ih, const float* __restrict__ b_hh,
    const float* __restrict__ W_fc, const float* __restrict__ b_fc,
    const float* __restrict__ emb, float* __restrict__ out)
{
    __shared__ float4   gtab[VOCAB][HID];     // per-token gate preacts (i,f,g,o) 14 KB
    __shared__ _Float16 hbuf[CHUNK][HID];     // h ring buffer, f16, 16 KB
    __shared__ int      toks[CHUNK];          // 256 B
    // Occupancy shaper: pushes static LDS to ~129 KB -> backend occupancy model
    // says 1 block/CU -> 2 waves/SIMD -> register-pressure target 256 VGPRs.
    // (We really do run 1 block/CU: grid = 256 = #CUs.)
    __shared__ float    ldspad[24 * 1024];    // 96 KB

    const int tid  = threadIdx.x;
    const int b    = blockIdx.x;
    const int j    = tid >> 2;      // hidden unit 0..127
    const int r    = tid & 3;       // h slice 0..3
    const int lane = tid & 63;
    const int wave = tid >> 6;

    // ---- W_hh: gates 0..3 of unit j, h columns [32r, 32r+32) -> 64 h2 VGPRs ----
    h2 w0[16], w1[16], w2[16], w3[16];
    {
        const float2* p0 = (const float2*)(W_hh + ((size_t)(0 * HID + j) * HID + r * 32));
        const float2* p1 = (const float2*)(W_hh + ((size_t)(1 * HID + j) * HID + r * 32));
        const float2* p2 = (const float2*)(W_hh + ((size_t)(2 * HID + j) * HID + r * 32));
        const float2* p3 = (const float2*)(W_hh + ((size_t)(3 * HID + j) * HID + r * 32));
        #pragma unroll
        for (int k = 0; k < 16; ++k) {
            float2 f0 = p0[k], f1 = p1[k], f2 = p2[k], f3 = p3[k];
            h2 a; a.x = (_Float16)f0.x; a.y = (_Float16)f0.y; w0[k] = a;
            h2 bq; bq.x = (_Float16)f1.x; bq.y = (_Float16)f1.y; w1[k] = bq;
            h2 cq; cq.x = (_Float16)f2.x; cq.y = (_Float16)f2.y; w2[k] = cq;
            h2 dq; dq.x = (_Float16)f3.x; dq.y = (_Float16)f3.y; w3[k] = dq;
        }
    }
    #pragma unroll
    for (int k = 0; k < 16; ++k) { KEEP(w0[k]); KEEP(w1[k]); KEEP(w2[k]); KEEP(w3[k]); }

    // ---- token -> gate preact table: gtab[v][j][gate r] (thread builds row g=r*128+j)
    {
        const int g = r * HID + j;
        float wih[EMBD];
        #pragma unroll
        for (int e = 0; e < EMBD; ++e) wih[e] = W_ih[g * EMBD + e];
        float bb = b_ih[g] + b_hh[g];
        #pragma unroll
        for (int v = 0; v < VOCAB; ++v) {
            float a = bb;
            #pragma unroll
            for (int e = 0; e < EMBD; ++e) a += wih[e] * emb[v * EMBD + e];
            ((float*)&gtab[v][j])[r] = a;
        }
    }

    // ---- state ----
    float c = c0[b * HID + j];      // replicated across the 4 slice lanes of unit j
    if (tid < HID) hbuf[CHUNK - 1][tid] = (_Float16)0.f;   // h(-1)=0 in slot CHUNK-1

    // ---- FC weights hoisted (lane-sliced columns) ----
    float wfc0[OUTD], wfc1[OUTD], bfc[OUTD];
    #pragma unroll
    for (int o = 0; o < OUTD; ++o) {
        wfc0[o] = W_fc[o * HID + 2 * lane];
        wfc1[o] = W_fc[o * HID + 2 * lane + 1];
        bfc[o]  = b_fc[o];
    }
    __syncthreads();

    #pragma unroll 1
    for (int ch = 0; ch < NCHUNK; ++ch) {
        const int t0 = ch * CHUNK;
        if (tid < CHUNK) toks[tid] = inputs[(size_t)b * TT + t0 + tid];
        __syncthreads();

        #pragma unroll 1
        for (int s = 0; s < CHUNK; ++s) {
            const int prev = (s + CHUNK - 1) & (CHUNK - 1);

            // h slice read: 4 ds_read_b128 (4 distinct lines/wave, 2-way bank alias = free)
            const uint4* hp = (const uint4*)&hbuf[prev][r * 32];
            float a0 = 0.f, a1 = 0.f, a2 = 0.f, a3 = 0.f;
            #pragma unroll
            for (int k = 0; k < 4; ++k) {
                uint4 v = hp[k];
                h2 hx = __builtin_bit_cast(h2, v.x);
                h2 hy = __builtin_bit_cast(h2, v.y);
                h2 hz = __builtin_bit_cast(h2, v.z);
                h2 hw = __builtin_bit_cast(h2, v.w);
                a0 = dot2(w0[4*k+0], hx, a0); a0 = dot2(w0[4*k+1], hy, a0);
                a0 = dot2(w0[4*k+2], hz, a0); a0 = dot2(w0[4*k+3], hw, a0);
                a1 = dot2(w1[4*k+0], hx, a1); a1 = dot2(w1[4*k+1], hy, a1);
                a1 = dot2(w1[4*k+2], hz, a1); a1 = dot2(w1[4*k+3], hw, a1);
                a2 = dot2(w2[4*k+0], hx, a2); a2 = dot2(w2[4*k+1], hy, a2);
                a2 = dot2(w2[4*k+2], hz, a2); a2 = dot2(w2[4*k+3], hw, a2);
                a3 = dot2(w3[4*k+0], hx, a3); a3 = dot2(w3[4*k+1], hy, a3);
                a3 = dot2(w3[4*k+2], hz, a3); a3 = dot2(w3[4*k+3], hw, a3);
            }
            // quad reduce over the 4 h-slices -> every quad lane gets full 4 gate sums
            a0 += __shfl_xor(a0, 1, 64); a0 += __shfl_xor(a0, 2, 64);
            a1 += __shfl_xor(a1, 1, 64); a1 += __shfl_xor(a1, 2, 64);
            a2 += __shfl_xor(a2, 1, 64); a2 += __shfl_xor(a2, 2, 64);
            a3 += __shfl_xor(a3, 1, 64); a3 += __shfl_xor(a3, 2, 64);

            const float4 xg = gtab[toks[s]][j];   // quad-uniform b128
            float gi = sigmoid_f(a0 + xg.x);
            float gf = sigmoid_f(a1 + xg.y);
            float gg = tanh_f  (a2 + xg.z);
            float go = sigmoid_f(a3 + xg.w);
            c = gf * c + gi * gg;                 // replicated x4, identical values
            float h = go * tanh_f(c);
            if (r == 0) hbuf[s][j] = (_Float16)h;
            __syncthreads();
        }

        // ---- FC + softmax flush for this chunk ----
        #pragma unroll 1
        for (int i = 0; i < CHUNK / 8; ++i) {
            const int row = wave * (CHUNK / 8) + i;   // timestep row in chunk
            h2 hv = ((const h2*)&hbuf[row][0])[lane];
            float h0 = (float)hv.x, h1 = (float)hv.y;
            float acc[OUTD];
            #pragma unroll
            for (int o = 0; o < OUTD; ++o) acc[o] = wfc0[o] * h0 + wfc1[o] * h1;
            #pragma unroll
            for (int off = 32; off >= 1; off >>= 1) {
                #pragma unroll
                for (int o = 0; o < OUTD; ++o) acc[o] += __shfl_xor(acc[o], off, 64);
            }
            if (lane == 0) {
                float m = -1e30f;
                #pragma unroll
                for (int o = 0; o < OUTD; ++o) { acc[o] += bfc[o]; m = fmaxf(m, acc[o]); }
                float e[OUTD], ssum = 0.f;
                #pragma unroll
                for (int o = 0; o < OUTD; ++o) { e[o] = v_exp2(1.44269504f * (acc[o] - m)); ssum += e[o]; }
                float inv = v_rcp(ssum);
                float* po = out + ((size_t)b * TT + (t0 + row)) * OUTD;
                #pragma unroll
                for (int o = 0; o < OUTD; ++o) po[o] = e[o] * inv;
            }
        }
        __syncthreads();
    }

    // ---- Keep ldspad allocated: volatile LDS write+read feeding a global store,
    // inside a data-dependent never-true branch (tokens are 0..6). Volatile ops
    // cannot be DCE'd, so the 96 KB array survives to the occupancy model.
    if (__builtin_expect(inputs[0] == -2147483647, 0)) {
        volatile float* vp = ldspad;
        vp[tid] = (float)tid;
        out[tid] = vp[tid + 1];
    }
}

extern "C" void kernel_launch(void* const* d_in, const int* in_sizes, int n_in,
                              void* d_out, int out_size, void* d_ws, size_t ws_size,
                              hipStream_t stream) {
    const int*   inputs = (const int*)  d_in[0];
    const float* c0     = (const float*)d_in[1];
    const float* W_ih   = (const float*)d_in[2];
    const float* W_hh   = (const float*)d_in[3];
    const float* b_ih   = (const float*)d_in[4];
    const float* b_hh   = (const float*)d_in[5];
    const float* W_fc   = (const float*)d_in[6];
    const float* b_fc   = (const float*)d_in[7];
    const float* emb    = (const float*)d_in[8];
    float* out = (float*)d_out;

    lstm_persist<<<BB, 512, 0, stream>>>(inputs, c0, W_ih, W_hh, b_ih, b_hh,
                                         W_fc, b_fc, emb, out);
}